// Round 9
// baseline (547.612 us; speedup 1.0000x reference)
//
#include <hip/hip_runtime.h>

#define N_NODES 10000
#define N_EDGES 640000
#define FEATS 128
#define NPB 64                                  // nodes owned per agg block
#define AGG_BLOCKS ((N_NODES + NPB - 1) / NPB)  // 157
#define QCAP 6144                               // LDS queue cap (mean 4096, sigma~64)
#define WCVT_BLOCKS (FEATS * FEATS / 4 / 256)   // 16  (float4 granules)
#define XCVT_BLOCKS (N_NODES * FEATS / 4 / 256) // 1250
#define GEMM_WAVES (N_NODES / 16)               // 625 row-tiles
#define GEMM_GRID ((GEMM_WAVES + 3) / 4)        // 157 blocks x 4 waves

typedef __attribute__((ext_vector_type(8))) short short8;
typedef __attribute__((ext_vector_type(4))) float f32x4;

// fp32 -> bf16 (RNE) and back
static __device__ __forceinline__ unsigned short f2bf(float f) {
    unsigned int u = __float_as_uint(f);
    u = (u + 0x7FFFu + ((u >> 16) & 1u)) >> 16;
    return (unsigned short)u;
}
static __device__ __forceinline__ float bf2f(unsigned short h) {
    return __uint_as_float((unsigned int)h << 16);
}

// ---------------------------------------------------------------------------
// Prep: W -> wb (bf16 row-major [out][in]); x -> xhi/xlo (bf16 hi/lo split,
// row-major [node][feat]). No transpose needed: MFMA B-operand wants B[n][k],
// which IS W's layout.
// ---------------------------------------------------------------------------
__global__ void prep_kernel(const float* __restrict__ x,
                            const float* __restrict__ W,
                            unsigned short* __restrict__ xhi,
                            unsigned short* __restrict__ xlo,
                            unsigned short* __restrict__ wb) {
    int blk = blockIdx.x;
    int tid = threadIdx.x;
    if (blk < WCVT_BLOCKS) {
        int i = blk * 256 + tid;                 // float4 index, 4096 total
        float4 v = reinterpret_cast<const float4*>(W)[i];
        ushort4 h;
        h.x = f2bf(v.x); h.y = f2bf(v.y); h.z = f2bf(v.z); h.w = f2bf(v.w);
        reinterpret_cast<ushort4*>(wb)[i] = h;
    } else {
        int i = (blk - WCVT_BLOCKS) * 256 + tid; // float4 index, 320000 total
        float4 v = reinterpret_cast<const float4*>(x)[i];
        ushort4 h, l;
        h.x = f2bf(v.x); h.y = f2bf(v.y); h.z = f2bf(v.z); h.w = f2bf(v.w);
        l.x = f2bf(v.x - bf2f(h.x)); l.y = f2bf(v.y - bf2f(h.y));
        l.z = f2bf(v.z - bf2f(h.z)); l.w = f2bf(v.w - bf2f(h.w));
        reinterpret_cast<ushort4*>(xhi)[i] = h;
        reinterpret_cast<ushort4*>(xlo)[i] = l;
    }
}

// ---------------------------------------------------------------------------
// MFMA GEMM: ybf = bf16(x @ W^T). One wave per 16-row tile, 8 col-tiles,
// K=128 in 4 chunks. 2-term split (xhi + xlo) keeps input rounding ~fp32.
// A-frag: A[m=lane&15][k=(lane>>4)*8+j]; B-frag: B[n=lane&15][k=...] = W rows.
// C/D: col=lane&15, row=(lane>>4)*4+reg  [guide m89-verified].
// ---------------------------------------------------------------------------
__global__ __launch_bounds__(256) void gemm_kernel(const unsigned short* __restrict__ xhi,
                                                   const unsigned short* __restrict__ xlo,
                                                   const unsigned short* __restrict__ wb,
                                                   unsigned short* __restrict__ ybf) {
    int wave = blockIdx.x * 4 + (threadIdx.x >> 6);
    if (wave >= GEMM_WAVES) return;
    int lane = threadIdx.x & 63;
    int m0 = wave * 16;
    int mrow = m0 + (lane & 15);
    int kbase = (lane >> 4) * 8;

    short8 ahi[4], alo[4];
    #pragma unroll
    for (int c = 0; c < 4; ++c) {
        ahi[c] = *reinterpret_cast<const short8*>(xhi + mrow * FEATS + c * 32 + kbase);
        alo[c] = *reinterpret_cast<const short8*>(xlo + mrow * FEATS + c * 32 + kbase);
    }

    int nr = lane & 15;
    int rbase = m0 + (lane >> 4) * 4;
    #pragma unroll
    for (int t = 0; t < 8; ++t) {
        f32x4 acc = {0.f, 0.f, 0.f, 0.f};
        #pragma unroll
        for (int c = 0; c < 4; ++c) {
            short8 bf = *reinterpret_cast<const short8*>(wb + (t * 16 + nr) * FEATS + c * 32 + kbase);
            acc = __builtin_amdgcn_mfma_f32_16x16x32_bf16(ahi[c], bf, acc, 0, 0, 0);
            acc = __builtin_amdgcn_mfma_f32_16x16x32_bf16(alo[c], bf, acc, 0, 0, 0);
        }
        int col = t * 16 + (lane & 15);
        #pragma unroll
        for (int r = 0; r < 4; ++r) {
            ybf[(rbase + r) * FEATS + col] = f2bf(acc[r]);
        }
    }
}

// ---------------------------------------------------------------------------
// Aggregate: block owns nodes [base, base+NPB). Scan all dst (L2-broadcast),
// queue matches in LDS, counting-sort by local node, then per-node gather of
// ybf rows with shuffle-broadcast indices (32 independent loads in flight).
// out[n] = bf(y[n]) + b + sum ybf[src]. No global atomics, no CSR arrays.
// ---------------------------------------------------------------------------
__global__ __launch_bounds__(256) void agg_kernel(const unsigned short* __restrict__ ybf,
                                                  const int* __restrict__ src,
                                                  const int* __restrict__ dst,
                                                  const float* __restrict__ b,
                                                  float* __restrict__ out) {
    __shared__ int q[QCAP];        // packed (local<<16)|src
    __shared__ int q2[QCAP];       // src, grouped by local node
    __shared__ int cnts[NPB];
    __shared__ int offs[NPB + 1];
    __shared__ int curs[NPB];
    __shared__ int qn;

    int tid = threadIdx.x;
    int base = blockIdx.x * NPB;
    int nloc = N_NODES - base; if (nloc > NPB) nloc = NPB;

    if (tid == 0) qn = 0;
    if (tid < NPB) cnts[tid] = 0;
    __syncthreads();

    // Phase 1: scan dst stream (int4), queue matching edges.
    const int4* dst4 = reinterpret_cast<const int4*>(dst);
    for (int i = tid; i < N_EDGES / 4; i += 256) {
        int4 d = dst4[i];
        int e = i * 4;
        unsigned l0 = (unsigned)(d.x - base);
        if (l0 < (unsigned)nloc) {
            int p = atomicAdd(&qn, 1);
            if (p < QCAP) { q[p] = ((int)l0 << 16) | src[e]; atomicAdd(&cnts[l0], 1); }
        }
        unsigned l1 = (unsigned)(d.y - base);
        if (l1 < (unsigned)nloc) {
            int p = atomicAdd(&qn, 1);
            if (p < QCAP) { q[p] = ((int)l1 << 16) | src[e + 1]; atomicAdd(&cnts[l1], 1); }
        }
        unsigned l2 = (unsigned)(d.z - base);
        if (l2 < (unsigned)nloc) {
            int p = atomicAdd(&qn, 1);
            if (p < QCAP) { q[p] = ((int)l2 << 16) | src[e + 2]; atomicAdd(&cnts[l2], 1); }
        }
        unsigned l3 = (unsigned)(d.w - base);
        if (l3 < (unsigned)nloc) {
            int p = atomicAdd(&qn, 1);
            if (p < QCAP) { q[p] = ((int)l3 << 16) | src[e + 3]; atomicAdd(&cnts[l3], 1); }
        }
    }
    __syncthreads();

    // Wave 0: shuffle-scan of 64 counts -> offs (exclusive), curs = offs.
    if (tid < 64) {
        int c = cnts[tid];
        int v = c;
        #pragma unroll
        for (int d_ = 1; d_ < 64; d_ <<= 1) {
            int u = __shfl_up(v, d_, 64);
            if (tid >= d_) v += u;
        }
        offs[tid + 1] = v;
        if (tid == 0) offs[0] = 0;
        curs[tid] = v - c;            // exclusive prefix
    }
    __syncthreads();

    // Phase 2: place into q2 grouped by local node.
    int nq = offs[NPB];
    for (int i = tid; i < nq; i += 256) {
        int v = q[i];
        int l = (unsigned)v >> 16;
        int p = atomicAdd(&curs[l], 1);
        q2[p] = v & 0xFFFF;
    }
    __syncthreads();

    // Phase 3: gather. Group g (32 lanes) owns nodes l = g, g+8, ...
    int tx = tid & 31;
    int g = tid >> 5;
    for (int l = g; l < nloc; l += 8) {
        int s0 = offs[l];
        int s1 = offs[l + 1];
        float4 a = make_float4(0.f, 0.f, 0.f, 0.f);
        int i = s0;
        while (i < s1) {
            int rem = s1 - i;
            int count = rem < 32 ? rem : 32;
            int myv = (i + tx < s1) ? q2[i + tx] : 0;
            #pragma unroll
            for (int j = 0; j < 32; ++j) {
                if (j < count) {
                    int s = __shfl(myv, j, 32);
                    ushort4 v = reinterpret_cast<const ushort4*>(ybf + s * FEATS)[tx];
                    a.x += bf2f(v.x); a.y += bf2f(v.y);
                    a.z += bf2f(v.z); a.w += bf2f(v.w);
                }
            }
            i += 32;
        }
        int node = base + l;
        ushort4 sv = reinterpret_cast<const ushort4*>(ybf + node * FEATS)[tx];
        float4 bs = reinterpret_cast<const float4*>(b)[tx];
        float4 o;
        o.x = a.x + bf2f(sv.x) + bs.x;
        o.y = a.y + bf2f(sv.y) + bs.y;
        o.z = a.z + bf2f(sv.z) + bs.z;
        o.w = a.w + bf2f(sv.w) + bs.w;
        reinterpret_cast<float4*>(out + node * FEATS)[tx] = o;
    }
}

// ---------------------------------------------------------------------------
extern "C" void kernel_launch(void* const* d_in, const int* in_sizes, int n_in,
                              void* d_out, int out_size, void* d_ws, size_t ws_size,
                              hipStream_t stream) {
    const float* x   = (const float*)d_in[0];
    const int*   src = (const int*)d_in[1];
    const int*   dst = (const int*)d_in[2];
    const float* W   = (const float*)d_in[3];
    const float* b   = (const float*)d_in[4];
    float* out = (float*)d_out;

    // Workspace: xhi [N*F u16] | xlo [N*F u16] | wb [128*128 u16] | ybf [N*F u16]
    unsigned short* xhi = (unsigned short*)d_ws;
    unsigned short* xlo = xhi + N_NODES * FEATS;
    unsigned short* wb  = xlo + N_NODES * FEATS;
    unsigned short* ybf = wb + FEATS * FEATS;

    prep_kernel<<<WCVT_BLOCKS + XCVT_BLOCKS, 256, 0, stream>>>(x, W, xhi, xlo, wb);
    gemm_kernel<<<GEMM_GRID, 256, 0, stream>>>(xhi, xlo, wb, ybf);
    agg_kernel<<<AGG_BLOCKS, 256, 0, stream>>>(ybf, src, dst, b, out);
}

// Round 10
// 123.108 us; speedup vs baseline: 4.4482x; 4.4482x over previous
//
#include <hip/hip_runtime.h>

#define N_NODES 10000
#define N_EDGES 640000
#define FEATS 128
#define NBKT 625                 // 16-node buckets: bucket = dst >> 4 (10000/16 exact)
#define CAPB 2048                // per-bucket capacity (mean 1024, sigma ~32 -> safe)
#define GSTRIDE 16               // gcur padding: 1 counter per 64B line
#define GEMM_WAVES 625           // one wave per 16-row tile
#define GEMM_GRID 157            // x4 waves
#define P1_BLOCKS 79             // 8192 edges per pass-1 block
#define WCVT_BLOCKS 16           // W float4 granules / 256
#define XCVT_BLOCKS 1250         // x float4 granules / 256
#define CLR_BLOCKS 40            // 10000 gcur ints / 256

typedef __attribute__((ext_vector_type(8))) short short8;
typedef __attribute__((ext_vector_type(4))) float f32x4;

static __device__ __forceinline__ unsigned short f2bf(float f) {
    unsigned int u = __float_as_uint(f);
    u = (u + 0x7FFFu + ((u >> 16) & 1u)) >> 16;
    return (unsigned short)u;
}
static __device__ __forceinline__ float bf2f(unsigned short h) {
    return __uint_as_float((unsigned int)h << 16);
}

// ---------------------------------------------------------------------------
// Prep: W -> wb (bf16 [out][in]); x -> xhi/xlo (bf16 hi/lo split); clear gcur.
// ---------------------------------------------------------------------------
__global__ void prep_kernel(const float* __restrict__ x,
                            const float* __restrict__ W,
                            unsigned short* __restrict__ xhi,
                            unsigned short* __restrict__ xlo,
                            unsigned short* __restrict__ wb,
                            int* __restrict__ gcur) {
    int blk = blockIdx.x;
    int tid = threadIdx.x;
    if (blk < WCVT_BLOCKS) {
        int i = blk * 256 + tid;                 // 4096 float4s
        float4 v = reinterpret_cast<const float4*>(W)[i];
        ushort4 h;
        h.x = f2bf(v.x); h.y = f2bf(v.y); h.z = f2bf(v.z); h.w = f2bf(v.w);
        reinterpret_cast<ushort4*>(wb)[i] = h;
    } else if (blk < WCVT_BLOCKS + XCVT_BLOCKS) {
        int i = (blk - WCVT_BLOCKS) * 256 + tid; // 320000 float4s
        float4 v = reinterpret_cast<const float4*>(x)[i];
        ushort4 h, l;
        h.x = f2bf(v.x); h.y = f2bf(v.y); h.z = f2bf(v.z); h.w = f2bf(v.w);
        l.x = f2bf(v.x - bf2f(h.x)); l.y = f2bf(v.y - bf2f(h.y));
        l.z = f2bf(v.z - bf2f(h.z)); l.w = f2bf(v.w - bf2f(h.w));
        reinterpret_cast<ushort4*>(xhi)[i] = h;
        reinterpret_cast<ushort4*>(xlo)[i] = l;
    } else {
        int i = (blk - WCVT_BLOCKS - XCVT_BLOCKS) * 256 + tid;
        if (i < NBKT * GSTRIDE) gcur[i] = 0;
    }
}

// ---------------------------------------------------------------------------
// Fused:
//  - blocks [0, GEMM_GRID): MFMA GEMM ybf = bf16(x @ W^T). One wave per
//    16-row tile, 2-term bf16 split (R9-verified numerics).
//  - blocks [GEMM_GRID, +P1_BLOCKS): radix partition pass 1. Per block:
//    LDS histogram of 8192 edges over 625 buckets -> one global atomic per
//    (block,bucket) reserves a dense range -> scatter packed (local<<16|src)
//    contiguously (~13 entries = ~1 cache line per bucket per block).
// ---------------------------------------------------------------------------
__global__ __launch_bounds__(256) void fused_kernel(const unsigned short* __restrict__ xhi,
                                                    const unsigned short* __restrict__ xlo,
                                                    const unsigned short* __restrict__ wb,
                                                    const int* __restrict__ src,
                                                    const int* __restrict__ dst,
                                                    unsigned short* __restrict__ ybf,
                                                    int* __restrict__ gcur,
                                                    int* __restrict__ ebuf) {
    __shared__ int lhist[NBKT];
    __shared__ int sbase[NBKT];
    __shared__ int lcur[NBKT];
    int tid = threadIdx.x;

    if (blockIdx.x < GEMM_GRID) {
        // ---------------- MFMA gemm ----------------
        int wave = blockIdx.x * 4 + (tid >> 6);
        if (wave >= GEMM_WAVES) return;
        int lane = tid & 63;
        int m0 = wave * 16;
        int mrow = m0 + (lane & 15);
        int kbase = (lane >> 4) * 8;

        short8 ahi[4], alo[4];
        #pragma unroll
        for (int c = 0; c < 4; ++c) {
            ahi[c] = *reinterpret_cast<const short8*>(xhi + mrow * FEATS + c * 32 + kbase);
            alo[c] = *reinterpret_cast<const short8*>(xlo + mrow * FEATS + c * 32 + kbase);
        }

        int nr = lane & 15;
        int rbase = m0 + (lane >> 4) * 4;
        #pragma unroll
        for (int t = 0; t < 8; ++t) {
            f32x4 acc = {0.f, 0.f, 0.f, 0.f};
            #pragma unroll
            for (int c = 0; c < 4; ++c) {
                short8 bf = *reinterpret_cast<const short8*>(wb + (t * 16 + nr) * FEATS + c * 32 + kbase);
                acc = __builtin_amdgcn_mfma_f32_16x16x32_bf16(ahi[c], bf, acc, 0, 0, 0);
                acc = __builtin_amdgcn_mfma_f32_16x16x32_bf16(alo[c], bf, acc, 0, 0, 0);
            }
            int col = t * 16 + (lane & 15);
            #pragma unroll
            for (int r = 0; r < 4; ++r) {
                ybf[(rbase + r) * FEATS + col] = f2bf(acc[r]);
            }
        }
        return;
    }

    // ---------------- pass 1: dense radix partition ----------------
    int blk = blockIdx.x - GEMM_GRID;
    for (int i = tid; i < NBKT; i += 256) lhist[i] = 0;
    __syncthreads();

    const int4* dst4 = reinterpret_cast<const int4*>(dst);
    const int4* src4 = reinterpret_cast<const int4*>(src);
    int i4base = blk * 2048;                    // 8192 edges = 2048 int4

    // Phase A: histogram
    #pragma unroll
    for (int j = 0; j < 8; ++j) {
        int i4 = i4base + j * 256 + tid;
        if (i4 < N_EDGES / 4) {
            int4 d = dst4[i4];
            atomicAdd(&lhist[d.x >> 4], 1);
            atomicAdd(&lhist[d.y >> 4], 1);
            atomicAdd(&lhist[d.z >> 4], 1);
            atomicAdd(&lhist[d.w >> 4], 1);
        }
    }
    __syncthreads();

    // Reserve dense ranges: one global atomic per non-empty (block,bucket).
    for (int i = tid; i < NBKT; i += 256) {
        int c = lhist[i];
        int base = c ? atomicAdd(&gcur[i * GSTRIDE], c) : 0;
        sbase[i] = i * CAPB + base;
        lcur[i] = 0;
    }
    __syncthreads();

    // Phase B: scatter packed entries densely.
    #pragma unroll
    for (int j = 0; j < 8; ++j) {
        int i4 = i4base + j * 256 + tid;
        if (i4 < N_EDGES / 4) {
            int4 d = dst4[i4];
            int4 s = src4[i4];
            int b0 = d.x >> 4, b1 = d.y >> 4, b2 = d.z >> 4, b3 = d.w >> 4;
            int p0 = atomicAdd(&lcur[b0], 1);
            int p1 = atomicAdd(&lcur[b1], 1);
            int p2 = atomicAdd(&lcur[b2], 1);
            int p3 = atomicAdd(&lcur[b3], 1);
            int a0 = sbase[b0] + p0; if (a0 < (b0 + 1) * CAPB) ebuf[a0] = ((d.x & 15) << 16) | s.x;
            int a1 = sbase[b1] + p1; if (a1 < (b1 + 1) * CAPB) ebuf[a1] = ((d.y & 15) << 16) | s.y;
            int a2 = sbase[b2] + p2; if (a2 < (b2 + 1) * CAPB) ebuf[a2] = ((d.z & 15) << 16) | s.z;
            int a3 = sbase[b3] + p3; if (a3 < (b3 + 1) * CAPB) ebuf[a3] = ((d.w & 15) << 16) | s.w;
        }
    }
}

// ---------------------------------------------------------------------------
// Pass 2: one block per 16-node bucket. Read packed edges (dense ~4 KB),
// LDS counting-sort by local node, then shuffle-broadcast gather of ybf rows
// (L2-resident). out[n] = ybf[n] + b + sum ybf[src].
// ---------------------------------------------------------------------------
__global__ __launch_bounds__(256) void pass2_kernel(const unsigned short* __restrict__ ybf,
                                                    const int* __restrict__ ebuf,
                                                    const int* __restrict__ gcur,
                                                    const float* __restrict__ b,
                                                    float* __restrict__ out) {
    __shared__ int q2[CAPB];           // 8 KB: src grouped by local node
    __shared__ int cnts[16];
    __shared__ int offs[17];
    __shared__ int curs[16];
    int bkt = blockIdx.x;
    int tid = threadIdx.x;

    int cnt = gcur[bkt * GSTRIDE];
    if (cnt > CAPB) cnt = CAPB;
    if (tid < 16) cnts[tid] = 0;
    __syncthreads();

    const int* eb = ebuf + bkt * CAPB;
    for (int i = tid; i < cnt; i += 256) atomicAdd(&cnts[eb[i] >> 16], 1);
    __syncthreads();

    if (tid == 0) {
        int a = 0;
        #pragma unroll
        for (int l = 0; l < 16; ++l) { offs[l] = a; curs[l] = a; a += cnts[l]; }
        offs[16] = a;
    }
    __syncthreads();

    for (int i = tid; i < cnt; i += 256) {
        int v = eb[i];
        int p = atomicAdd(&curs[v >> 16], 1);
        q2[p] = v & 0xFFFF;
    }
    __syncthreads();

    // Gather: 8 groups of 32 lanes; group g handles local nodes g and g+8.
    int tx = tid & 31;
    int g = tid >> 5;
    for (int l = g; l < 16; l += 8) {
        int s0 = offs[l];
        int s1 = offs[l + 1];
        float4 a = make_float4(0.f, 0.f, 0.f, 0.f);
        for (int i = s0; i < s1; i += 32) {
            int count = s1 - i; if (count > 32) count = 32;
            int myv = (i + tx < s1) ? q2[i + tx] : 0;
            #pragma unroll
            for (int j = 0; j < 32; ++j) {
                if (j < count) {
                    int s = __shfl(myv, j, 32);
                    ushort4 v = reinterpret_cast<const ushort4*>(ybf + s * FEATS)[tx];
                    a.x += bf2f(v.x); a.y += bf2f(v.y);
                    a.z += bf2f(v.z); a.w += bf2f(v.w);
                }
            }
        }
        int node = bkt * 16 + l;
        ushort4 sv = reinterpret_cast<const ushort4*>(ybf + node * FEATS)[tx];
        float4 bs = reinterpret_cast<const float4*>(b)[tx];
        float4 o;
        o.x = a.x + bf2f(sv.x) + bs.x;
        o.y = a.y + bf2f(sv.y) + bs.y;
        o.z = a.z + bf2f(sv.z) + bs.z;
        o.w = a.w + bf2f(sv.w) + bs.w;
        reinterpret_cast<float4*>(out + node * FEATS)[tx] = o;
    }
}

// ---------------------------------------------------------------------------
extern "C" void kernel_launch(void* const* d_in, const int* in_sizes, int n_in,
                              void* d_out, int out_size, void* d_ws, size_t ws_size,
                              hipStream_t stream) {
    const float* x   = (const float*)d_in[0];
    const int*   src = (const int*)d_in[1];
    const int*   dst = (const int*)d_in[2];
    const float* W   = (const float*)d_in[3];
    const float* b   = (const float*)d_in[4];
    float* out = (float*)d_out;

    // Workspace: xhi [N*F u16] | xlo [N*F u16] | wb [F*F u16] | ybf [N*F u16]
    //            | gcur [NBKT*16 int] | ebuf [NBKT*CAPB int]
    unsigned short* xhi = (unsigned short*)d_ws;
    unsigned short* xlo = xhi + N_NODES * FEATS;
    unsigned short* wb  = xlo + N_NODES * FEATS;
    unsigned short* ybf = wb + FEATS * FEATS;
    int* gcur = (int*)(ybf + N_NODES * FEATS);
    int* ebuf = gcur + NBKT * GSTRIDE;

    prep_kernel<<<WCVT_BLOCKS + XCVT_BLOCKS + CLR_BLOCKS, 256, 0, stream>>>(x, W, xhi, xlo, wb, gcur);
    fused_kernel<<<GEMM_GRID + P1_BLOCKS, 256, 0, stream>>>(xhi, xlo, wb, src, dst, ybf, gcur, ebuf);
    pass2_kernel<<<NBKT, 256, 0, stream>>>(ybf, ebuf, gcur, b, out);
}

// Round 11
// 98.598 us; speedup vs baseline: 5.5540x; 1.2486x over previous
//
#include <hip/hip_runtime.h>

#define N_NODES 10000
#define N_EDGES 640000
#define FEATS 128
#define NBKT 625                 // 16-node buckets: bucket = dst >> 4 (10000/16 exact)
#define CAPB 2048                // per-bucket capacity (mean 1024, sigma ~32 -> safe)
#define GSTRIDE 16               // gcur padding: 1 counter per 64B line
#define GEMM_WAVES 625           // one wave per 16-row tile
#define GEMM_GRID 157            // x4 waves
#define P1_BLOCKS 79             // 8192 edges per pass-1 block
#define WCVT_BLOCKS 16           // W float4 granules / 256
#define XCVT_BLOCKS 1250         // x float4 granules / 256
#define CLR_BLOCKS 40            // 10000 gcur ints / 256

typedef __attribute__((ext_vector_type(8))) short short8;
typedef __attribute__((ext_vector_type(4))) float f32x4;

static __device__ __forceinline__ unsigned short f2bf(float f) {
    unsigned int u = __float_as_uint(f);
    u = (u + 0x7FFFu + ((u >> 16) & 1u)) >> 16;
    return (unsigned short)u;
}
static __device__ __forceinline__ float bf2f(unsigned short h) {
    return __uint_as_float((unsigned int)h << 16);
}

// ---------------------------------------------------------------------------
// Prep: W -> wb (bf16 [out][in]); x -> xhi/xlo (bf16 hi/lo split); clear gcur.
// ---------------------------------------------------------------------------
__global__ void prep_kernel(const float* __restrict__ x,
                            const float* __restrict__ W,
                            unsigned short* __restrict__ xhi,
                            unsigned short* __restrict__ xlo,
                            unsigned short* __restrict__ wb,
                            int* __restrict__ gcur) {
    int blk = blockIdx.x;
    int tid = threadIdx.x;
    if (blk < WCVT_BLOCKS) {
        int i = blk * 256 + tid;                 // 4096 float4s
        float4 v = reinterpret_cast<const float4*>(W)[i];
        ushort4 h;
        h.x = f2bf(v.x); h.y = f2bf(v.y); h.z = f2bf(v.z); h.w = f2bf(v.w);
        reinterpret_cast<ushort4*>(wb)[i] = h;
    } else if (blk < WCVT_BLOCKS + XCVT_BLOCKS) {
        int i = (blk - WCVT_BLOCKS) * 256 + tid; // 320000 float4s
        float4 v = reinterpret_cast<const float4*>(x)[i];
        ushort4 h, l;
        h.x = f2bf(v.x); h.y = f2bf(v.y); h.z = f2bf(v.z); h.w = f2bf(v.w);
        l.x = f2bf(v.x - bf2f(h.x)); l.y = f2bf(v.y - bf2f(h.y));
        l.z = f2bf(v.z - bf2f(h.z)); l.w = f2bf(v.w - bf2f(h.w));
        reinterpret_cast<ushort4*>(xhi)[i] = h;
        reinterpret_cast<ushort4*>(xlo)[i] = l;
    } else {
        int i = (blk - WCVT_BLOCKS - XCVT_BLOCKS) * 256 + tid;
        if (i < NBKT * GSTRIDE) gcur[i] = 0;
    }
}

// ---------------------------------------------------------------------------
// Fused:
//  - blocks [0, GEMM_GRID): MFMA GEMM ybf = bf16(x @ W^T). One wave per
//    16-row tile, 2-term bf16 split.
//  - blocks [GEMM_GRID, +P1_BLOCKS): radix partition pass 1: LDS histogram
//    of 8192 edges over 625 buckets -> one global atomic per (block,bucket)
//    reserves a dense range -> dense scatter of packed (local<<16|src).
// ---------------------------------------------------------------------------
__global__ __launch_bounds__(256) void fused_kernel(const unsigned short* __restrict__ xhi,
                                                    const unsigned short* __restrict__ xlo,
                                                    const unsigned short* __restrict__ wb,
                                                    const int* __restrict__ src,
                                                    const int* __restrict__ dst,
                                                    unsigned short* __restrict__ ybf,
                                                    int* __restrict__ gcur,
                                                    int* __restrict__ ebuf) {
    __shared__ int lhist[NBKT];
    __shared__ int sbase[NBKT];
    __shared__ int lcur[NBKT];
    int tid = threadIdx.x;

    if (blockIdx.x < GEMM_GRID) {
        // ---------------- MFMA gemm ----------------
        int wave = blockIdx.x * 4 + (tid >> 6);
        if (wave >= GEMM_WAVES) return;
        int lane = tid & 63;
        int m0 = wave * 16;
        int mrow = m0 + (lane & 15);
        int kbase = (lane >> 4) * 8;

        short8 ahi[4], alo[4];
        #pragma unroll
        for (int c = 0; c < 4; ++c) {
            ahi[c] = *reinterpret_cast<const short8*>(xhi + mrow * FEATS + c * 32 + kbase);
            alo[c] = *reinterpret_cast<const short8*>(xlo + mrow * FEATS + c * 32 + kbase);
        }

        int nr = lane & 15;
        int rbase = m0 + (lane >> 4) * 4;
        #pragma unroll
        for (int t = 0; t < 8; ++t) {
            f32x4 acc = {0.f, 0.f, 0.f, 0.f};
            #pragma unroll
            for (int c = 0; c < 4; ++c) {
                short8 bf = *reinterpret_cast<const short8*>(wb + (t * 16 + nr) * FEATS + c * 32 + kbase);
                acc = __builtin_amdgcn_mfma_f32_16x16x32_bf16(ahi[c], bf, acc, 0, 0, 0);
                acc = __builtin_amdgcn_mfma_f32_16x16x32_bf16(alo[c], bf, acc, 0, 0, 0);
            }
            int col = t * 16 + (lane & 15);
            #pragma unroll
            for (int r = 0; r < 4; ++r) {
                ybf[(rbase + r) * FEATS + col] = f2bf(acc[r]);
            }
        }
        return;
    }

    // ---------------- pass 1: dense radix partition ----------------
    int blk = blockIdx.x - GEMM_GRID;
    for (int i = tid; i < NBKT; i += 256) lhist[i] = 0;
    __syncthreads();

    const int4* dst4 = reinterpret_cast<const int4*>(dst);
    const int4* src4 = reinterpret_cast<const int4*>(src);
    int i4base = blk * 2048;                    // 8192 edges = 2048 int4

    #pragma unroll
    for (int j = 0; j < 8; ++j) {
        int i4 = i4base + j * 256 + tid;
        if (i4 < N_EDGES / 4) {
            int4 d = dst4[i4];
            atomicAdd(&lhist[d.x >> 4], 1);
            atomicAdd(&lhist[d.y >> 4], 1);
            atomicAdd(&lhist[d.z >> 4], 1);
            atomicAdd(&lhist[d.w >> 4], 1);
        }
    }
    __syncthreads();

    for (int i = tid; i < NBKT; i += 256) {
        int c = lhist[i];
        int base = c ? atomicAdd(&gcur[i * GSTRIDE], c) : 0;
        sbase[i] = i * CAPB + base;
        lcur[i] = 0;
    }
    __syncthreads();

    #pragma unroll
    for (int j = 0; j < 8; ++j) {
        int i4 = i4base + j * 256 + tid;
        if (i4 < N_EDGES / 4) {
            int4 d = dst4[i4];
            int4 s = src4[i4];
            int b0 = d.x >> 4, b1 = d.y >> 4, b2 = d.z >> 4, b3 = d.w >> 4;
            int p0 = atomicAdd(&lcur[b0], 1);
            int p1 = atomicAdd(&lcur[b1], 1);
            int p2 = atomicAdd(&lcur[b2], 1);
            int p3 = atomicAdd(&lcur[b3], 1);
            int a0 = sbase[b0] + p0; if (a0 < (b0 + 1) * CAPB) ebuf[a0] = ((d.x & 15) << 16) | s.x;
            int a1 = sbase[b1] + p1; if (a1 < (b1 + 1) * CAPB) ebuf[a1] = ((d.y & 15) << 16) | s.y;
            int a2 = sbase[b2] + p2; if (a2 < (b2 + 1) * CAPB) ebuf[a2] = ((d.z & 15) << 16) | s.z;
            int a3 = sbase[b3] + p3; if (a3 < (b3 + 1) * CAPB) ebuf[a3] = ((d.w & 15) << 16) | s.w;
        }
    }
}

// ---------------------------------------------------------------------------
// Pass 2 v2: one 1024-thread block per bucket, ONE WAVE PER LOCAL NODE
// (10000 waves total ~ 9.8/SIMD -> 4x R10's residency). Counting-sort the
// bucket's packed edges in LDS once, then wave w gathers its node's segment:
// lane = feat ushort2 (256 B/row coalesced), 8 independent row loads in
// flight, indices via wave-uniform LDS broadcast (conflict-free).
// All LDS indices masked &15 / clamped: robust against rocprof replay with
// poisoned workspace (R10's 30 ms outlier).
// ---------------------------------------------------------------------------
__global__ __launch_bounds__(1024) void pass2_kernel(const unsigned short* __restrict__ ybf,
                                                     const int* __restrict__ ebuf,
                                                     const int* __restrict__ gcur,
                                                     const float* __restrict__ b,
                                                     float* __restrict__ out) {
    __shared__ int q2[CAPB];           // 8 KB: src grouped by local node
    __shared__ int cnts[16];
    __shared__ int offs[17];
    __shared__ int curs[16];
    int bkt = blockIdx.x;
    int tid = threadIdx.x;

    int cnt = gcur[bkt * GSTRIDE];
    if (cnt > CAPB) cnt = CAPB;
    if (cnt < 0) cnt = 0;
    if (tid < 16) cnts[tid] = 0;
    __syncthreads();

    const int* eb = ebuf + bkt * CAPB;
    for (int i = tid; i < cnt; i += 1024) atomicAdd(&cnts[(eb[i] >> 16) & 15], 1);
    __syncthreads();

    if (tid == 0) {
        int a = 0;
        #pragma unroll
        for (int l = 0; l < 16; ++l) { offs[l] = a; curs[l] = a; a += cnts[l]; }
        offs[16] = a;
    }
    __syncthreads();

    for (int i = tid; i < cnt; i += 1024) {
        int v = eb[i];
        int p = atomicAdd(&curs[(v >> 16) & 15], 1);
        q2[p] = v & 0xFFFF;
    }
    __syncthreads();

    // Gather: wave w -> local node w; lane -> feats [lane*2, lane*2+1].
    int w = tid >> 6;
    int lane = tid & 63;
    int s0 = offs[w];
    int s1 = offs[w + 1];

    float ax = 0.f, ay = 0.f;
    int i = s0;
    for (; i + 8 <= s1; i += 8) {
        int sA[8];
        #pragma unroll
        for (int j = 0; j < 8; ++j) sA[j] = q2[i + j];   // wave-uniform broadcast
        #pragma unroll
        for (int j = 0; j < 8; ++j) {
            ushort2 v = *reinterpret_cast<const ushort2*>(ybf + sA[j] * FEATS + lane * 2);
            ax += bf2f(v.x); ay += bf2f(v.y);
        }
    }
    for (; i < s1; ++i) {
        int s = q2[i];
        ushort2 v = *reinterpret_cast<const ushort2*>(ybf + s * FEATS + lane * 2);
        ax += bf2f(v.x); ay += bf2f(v.y);
    }

    int node = bkt * 16 + w;
    ushort2 sv = *reinterpret_cast<const ushort2*>(ybf + node * FEATS + lane * 2);
    float2 bs = reinterpret_cast<const float2*>(b)[lane];
    float2 o;
    o.x = ax + bf2f(sv.x) + bs.x;
    o.y = ay + bf2f(sv.y) + bs.y;
    reinterpret_cast<float2*>(out + node * FEATS)[lane] = o;
}

// ---------------------------------------------------------------------------
extern "C" void kernel_launch(void* const* d_in, const int* in_sizes, int n_in,
                              void* d_out, int out_size, void* d_ws, size_t ws_size,
                              hipStream_t stream) {
    const float* x   = (const float*)d_in[0];
    const int*   src = (const int*)d_in[1];
    const int*   dst = (const int*)d_in[2];
    const float* W   = (const float*)d_in[3];
    const float* b   = (const float*)d_in[4];
    float* out = (float*)d_out;

    // Workspace: xhi [N*F u16] | xlo [N*F u16] | wb [F*F u16] | ybf [N*F u16]
    //            | gcur [NBKT*16 int] | ebuf [NBKT*CAPB int]
    unsigned short* xhi = (unsigned short*)d_ws;
    unsigned short* xlo = xhi + N_NODES * FEATS;
    unsigned short* wb  = xlo + N_NODES * FEATS;
    unsigned short* ybf = wb + FEATS * FEATS;
    int* gcur = (int*)(ybf + N_NODES * FEATS);
    int* ebuf = gcur + NBKT * GSTRIDE;

    prep_kernel<<<WCVT_BLOCKS + XCVT_BLOCKS + CLR_BLOCKS, 256, 0, stream>>>(x, W, xhi, xlo, wb, gcur);
    fused_kernel<<<GEMM_GRID + P1_BLOCKS, 256, 0, stream>>>(xhi, xlo, wb, src, dst, ybf, gcur, ebuf);
    pass2_kernel<<<NBKT, 1024, 0, stream>>>(ybf, ebuf, gcur, b, out);
}